// Round 1
// baseline (6032.559 us; speedup 1.0000x reference)
//
#include <hip/hip_runtime.h>
#include <stdint.h>

typedef unsigned short u16;
typedef __attribute__((ext_vector_type(8))) short bh8;   // 8 x bf16 bits (4 VGPR)
typedef __attribute__((ext_vector_type(4))) float f4;    // 4 x f32 (4 VGPR)

#define DEV static __device__ __forceinline__

DEV u16 f2bf(float f){ union{float f; uint32_t u;} v; v.f=f; uint32_t r=v.u + 0x7FFFu + ((v.u>>16)&1u); return (u16)(r>>16); }
DEV float bf2f(u16 u){ union{uint32_t u; float f;} v; v.u=((uint32_t)u)<<16; return v.f; }

DEV void mfma16(f4& d, bh8 a, bh8 b){
  asm("v_mfma_f32_16x16x32_bf16 %0, %1, %2, %0" : "+v"(d) : "v"(a), "v"(b));
}

// MFMA->VALU hazard fence with data dependence on all 16 accumulators
#define FENCE16(A) asm volatile("s_nop 7\ns_nop 7" : \
 "+v"(A[0][0]),"+v"(A[0][1]),"+v"(A[0][2]),"+v"(A[0][3]),\
 "+v"(A[1][0]),"+v"(A[1][1]),"+v"(A[1][2]),"+v"(A[1][3]),\
 "+v"(A[2][0]),"+v"(A[2][1]),"+v"(A[2][2]),"+v"(A[2][3]),\
 "+v"(A[3][0]),"+v"(A[3][1]),"+v"(A[3][2]),"+v"(A[3][3]))

#define GLD16(g,l) __builtin_amdgcn_global_load_lds( \
    (__attribute__((address_space(1))) void*)(void*)(g), \
    (__attribute__((address_space(3))) void*)(void*)(l), 16, 0, 0)

// ---------------------------------------------------------------- GEMM
// C[M,N] = A[M,K](bf16,lda=K) * Bt[N,K](bf16,ldb=K)^T + epilogue
// 128x128 tile, BK=32, 4 waves each 64x64 (4x4 frags of 16x16x32)
struct GemmP { const u16* A; const u16* B; int K; void* C; int ldc;
               const float* b0; const float* b1; const float* b2; const u16* res; };

template<int EPI>
__global__ __launch_bounds__(256)
void gemm_bt(GemmP p){
  __shared__ __align__(16) u16 As[128*32];
  __shared__ __align__(16) u16 Bs[128*32];
  const int t=threadIdx.x, l=t&63, w=t>>6, wr=w>>1, wc=w&1;
  const int m0=blockIdx.x*128, n0=blockIdx.y*128;
  const u16* Ab = p.A + (size_t)m0*p.K;
  const u16* Bb = p.B + (size_t)n0*p.K;
  const int srow=l>>2, scol=(l&3)*8;
  f4 acc[4][4] = {};
  for(int k0=0;k0<p.K;k0+=32){
#pragma unroll
    for(int i=0;i<2;i++){
      const int c=w*2+i;
      GLD16(Ab + (size_t)(c*16+srow)*p.K + k0 + scol, &As[c*512]);
      GLD16(Bb + (size_t)(c*16+srow)*p.K + k0 + scol, &Bs[c*512]);
    }
    __syncthreads();
    bh8 af[4], bfr[4];
#pragma unroll
    for(int m=0;m<4;m++) af[m] = *(const bh8*)&As[(wr*64+m*16+(l&15))*32 + (l>>4)*8];
#pragma unroll
    for(int n=0;n<4;n++) bfr[n] = *(const bh8*)&Bs[(wc*64+n*16+(l&15))*32 + (l>>4)*8];
#pragma unroll
    for(int m=0;m<4;m++)
#pragma unroll
      for(int n=0;n<4;n++) mfma16(acc[m][n], af[m], bfr[n]);
    __syncthreads();
  }
  FENCE16(acc);
  const int lc=l&15, lr=(l>>4)*4;
#pragma unroll
  for(int m=0;m<4;m++)
#pragma unroll
  for(int n=0;n<4;n++)
#pragma unroll
  for(int r=0;r<4;r++){
    const int gr = m0 + wr*64 + m*16 + lr + r;
    const int gc = n0 + wc*64 + n*16 + lc;
    float v = acc[m][n][r];
    if(EPI==0){ // qkv: 3-way bias select, bf16 out
      const float* bp = (gc<768)? p.b0 : (gc<1536? p.b1 : p.b2);
      const int bc = (gc<768)? gc : (gc<1536? gc-768 : gc-1536);
      ((u16*)p.C)[(size_t)gr*p.ldc + gc] = f2bf(v + bp[bc]);
    } else if(EPI==1){ // bias + residual, bf16 out
      v += p.b0[gc] + bf2f(p.res[(size_t)gr*p.ldc + gc]);
      ((u16*)p.C)[(size_t)gr*p.ldc + gc] = f2bf(v);
    } else if(EPI==2){ // bias + exact GELU, bf16 out
      v += p.b0[gc];
      v = 0.5f*v*(1.f + erff(v*0.70710678118f));
      ((u16*)p.C)[(size_t)gr*p.ldc + gc] = f2bf(v);
    } else { // slots: bias (first 64 cols), f32 out
      v += (gc<64)? p.b0[gc] : 0.f;
      ((float*)p.C)[(size_t)gr*p.ldc + gc] = v;
    }
  }
}

// ---------------------------------------------------------------- attention
// one block per (b,head); flash-style over 4 key-tiles of 64
__global__ __launch_bounds__(256)
void attn_kernel(const u16* __restrict__ qkv, const int* __restrict__ amask, u16* __restrict__ ctx){
  __shared__ __align__(16) u16 Ks[256*64];   // [key][d], XOR-swizzled
  __shared__ __align__(16) u16 Vt[64*256];   // [d][key], XOR-swizzled
  __shared__ __align__(16) u16 Ps[4*64*64];  // per-wave P tile, swizzled
  __shared__ float biasS[256];
  const int t=threadIdx.x, l=t&63, w=t>>6;
  const int b=blockIdx.x/12, h=blockIdx.x%12;
  biasS[t] = (1.f - (float)amask[b*256+t]) * -1e9f;
  const u16* kb = qkv + ((size_t)b*256)*2304 + 768 + h*64;
  const u16* vb = kb + 768;
#pragma unroll
  for(int i=0;i<8;i++){
    const int c = t + i*256;
    const int row = c>>3, seg = c&7;
    uint4 kv = *(const uint4*)(kb + (size_t)row*2304 + seg*8);
    const int ba = row*128 + seg*16;
    *(uint4*)((char*)Ks + (ba ^ ((row&7)<<4))) = kv;
    uint4 vv = *(const uint4*)(vb + (size_t)row*2304 + seg*8);
    const u16* pv = (const u16*)&vv;
#pragma unroll
    for(int j=0;j<8;j++){
      const int d = seg*8+j;
      const int bb = d*512 + row*2;
      *(u16*)((char*)Vt + (bb ^ ((d&7)<<4))) = pv[j];
    }
  }
  bh8 aq[4][2];
  const u16* qb = qkv + ((size_t)b*256 + w*64)*2304 + h*64;
#pragma unroll
  for(int m=0;m<4;m++)
#pragma unroll
    for(int ks=0;ks<2;ks++)
      aq[m][ks] = *(const bh8*)(qb + (size_t)(m*16+(l&15))*2304 + ks*32 + (l>>4)*8);
  __syncthreads();
  float mrun[4][4], lrun[4][4];
  f4 o[4][4] = {};
#pragma unroll
  for(int m=0;m<4;m++)
#pragma unroll
    for(int r=0;r<4;r++){ mrun[m][r] = -3e38f; lrun[m][r]=0.f; }
  u16* Pw = Ps + w*4096;
  for(int kt=0;kt<4;kt++){
    f4 sacc[4][4] = {};
#pragma unroll
    for(int ks=0;ks<2;ks++)
#pragma unroll
      for(int n=0;n<4;n++){
        const int row = kt*64 + n*16 + (l&15);
        const int by = row*128 + ks*64 + (l>>4)*16;
        bh8 bk = *(const bh8*)((const char*)Ks + (by ^ ((row&7)<<4)));
#pragma unroll
        for(int m=0;m<4;m++) mfma16(sacc[m][n], aq[m][ks], bk);
      }
    FENCE16(sacc);
#pragma unroll
    for(int m=0;m<4;m++){
      float rmax[4] = {-3e38f,-3e38f,-3e38f,-3e38f};
#pragma unroll
      for(int n=0;n<4;n++){
        const float bi = biasS[kt*64 + n*16 + (l&15)];
#pragma unroll
        for(int r=0;r<4;r++){
          float sv = sacc[m][n][r]*0.125f + bi;   // 1/sqrt(64) + mask bias
          sacc[m][n][r] = sv;
          rmax[r] = fmaxf(rmax[r], sv);
        }
      }
#pragma unroll
      for(int dd=1; dd<16; dd<<=1)
#pragma unroll
        for(int r=0;r<4;r++) rmax[r] = fmaxf(rmax[r], __shfl_xor(rmax[r], dd));
      float psum[4];
#pragma unroll
      for(int r=0;r<4;r++){
        const float mn = fmaxf(mrun[m][r], rmax[r]);
        const float corr = __expf(mrun[m][r] - mn);
        mrun[m][r] = mn;
        lrun[m][r] *= corr;
#pragma unroll
        for(int nd=0; nd<4; nd++) o[m][nd][r] *= corr;
        psum[r] = 0.f;
      }
#pragma unroll
      for(int n=0;n<4;n++)
#pragma unroll
        for(int r=0;r<4;r++){
          const float pvv = __expf(sacc[m][n][r] - mrun[m][r]);
          sacc[m][n][r] = pvv;
          psum[r] += pvv;
        }
#pragma unroll
      for(int dd=1; dd<16; dd<<=1)
#pragma unroll
        for(int r=0;r<4;r++) psum[r] += __shfl_xor(psum[r], dd);
#pragma unroll
      for(int r=0;r<4;r++) lrun[m][r] += psum[r];
#pragma unroll
      for(int n=0;n<4;n++)
#pragma unroll
        for(int r=0;r<4;r++){
          const int prow = m*16 + (l>>4)*4 + r;
          const int pcol = n*16 + (l&15);
          const int by = prow*128 + pcol*2;
          *(u16*)((char*)Pw + (by ^ ((prow&7)<<4))) = f2bf(sacc[m][n][r]);
        }
    }
#pragma unroll
    for(int ks=0;ks<2;ks++){
      bh8 ap[4];
#pragma unroll
      for(int m=0;m<4;m++){
        const int prow = m*16 + (l&15);
        const int by = prow*128 + (ks*32 + (l>>4)*8)*2;
        ap[m] = *(const bh8*)((const char*)Pw + (by ^ ((prow&7)<<4)));
      }
#pragma unroll
      for(int nd=0; nd<4; nd++){
        const int dR = nd*16 + (l&15);
        const int by = dR*512 + (kt*64 + ks*32 + (l>>4)*8)*2;
        bh8 bv = *(const bh8*)((const char*)Vt + (by ^ ((dR&7)<<4)));
#pragma unroll
        for(int m=0;m<4;m++) mfma16(o[m][nd], ap[m], bv);
      }
    }
  }
  FENCE16(o);
#pragma unroll
  for(int m=0;m<4;m++)
#pragma unroll
  for(int nd=0; nd<4; nd++)
#pragma unroll
  for(int r=0;r<4;r++){
    const int row = w*64 + m*16 + (l>>4)*4 + r;
    const float vv = o[m][nd][r] / lrun[m][r];
    ctx[((size_t)b*256 + row)*768 + h*64 + nd*16 + (l&15)] = f2bf(vv);
  }
}

// ---------------------------------------------------------------- LN / embed
__global__ void ln_kernel(const u16* __restrict__ in, const float* __restrict__ g,
                          const float* __restrict__ b, u16* __restrict__ out){
  const int row = blockIdx.x, t = threadIdx.x;
  __shared__ float red[8];
  const u16* rp = in + (size_t)row*768;
  float v[3]; float s=0.f, q=0.f;
#pragma unroll
  for(int i=0;i<3;i++){ float x = bf2f(rp[t + i*256]); v[i]=x; s+=x; q+=x*x; }
#pragma unroll
  for(int dd=1; dd<64; dd<<=1){ s += __shfl_xor(s,dd); q += __shfl_xor(q,dd); }
  if((t&63)==0){ red[t>>6]=s; red[4+(t>>6)]=q; }
  __syncthreads();
  s = red[0]+red[1]+red[2]+red[3];
  q = red[4]+red[5]+red[6]+red[7];
  const float mean = s*(1.f/768.f);
  float var = q*(1.f/768.f) - mean*mean; var = fmaxf(var, 0.f);
  const float rs = rsqrtf(var + 1e-12f);
  u16* op = out + (size_t)row*768;
#pragma unroll
  for(int i=0;i<3;i++){ const int hh=t+i*256; op[hh] = f2bf((v[i]-mean)*rs*g[hh] + b[hh]); }
}

__global__ void embed_ln(const int* __restrict__ ids, const int* __restrict__ tti,
    const float* __restrict__ we, const float* __restrict__ pe, const float* __restrict__ te,
    const float* __restrict__ g, const float* __restrict__ bb, u16* __restrict__ x){
  const int tok = blockIdx.x, t = threadIdx.x;
  __shared__ float red[8];
  const int id = ids[tok], tyid = tti[tok], s0 = tok & 255;
  float v[3]; float s=0.f,q=0.f;
#pragma unroll
  for(int i=0;i<3;i++){
    const int hh = t+i*256;
    float x0 = we[(size_t)id*768+hh] + pe[(size_t)s0*768+hh] + te[(size_t)tyid*768+hh];
    v[i]=x0; s+=x0; q+=x0*x0;
  }
#pragma unroll
  for(int dd=1; dd<64; dd<<=1){ s += __shfl_xor(s,dd); q += __shfl_xor(q,dd); }
  if((t&63)==0){ red[t>>6]=s; red[4+(t>>6)]=q; }
  __syncthreads();
  s = red[0]+red[1]+red[2]+red[3];
  q = red[4]+red[5]+red[6]+red[7];
  const float mean = s*(1.f/768.f);
  float var = q*(1.f/768.f) - mean*mean; var = fmaxf(var, 0.f);
  const float rs = rsqrtf(var + 1e-12f);
#pragma unroll
  for(int i=0;i<3;i++){ const int hh=t+i*256; x[(size_t)tok*768+hh] = f2bf((v[i]-mean)*rs*g[hh] + bb[hh]); }
}

// ---------------------------------------------------------------- weight transpose+cvt
__global__ void transpose_cvt(const float* __restrict__ src, u16* __restrict__ dst, int R, int C){
  __shared__ float sm[32][33];
  const int ntc = C>>5;
  const int tr = blockIdx.x/ntc, tc = blockIdx.x - tr*ntc;
  const int r0 = tr<<5, c0 = tc<<5;
  const int tx = threadIdx.x, ty2 = threadIdx.y;
#pragma unroll
  for(int i=0;i<4;i++) sm[ty2+i*8][tx] = src[(size_t)(r0+ty2+i*8)*C + c0+tx];
  __syncthreads();
#pragma unroll
  for(int i=0;i<4;i++) dst[(size_t)(c0+ty2+i*8)*R + r0+tx] = f2bf(sm[tx][ty2+i*8]);
}

__global__ void conv_layer(const float* __restrict__ Wq, const float* __restrict__ Wk,
    const float* __restrict__ Wv, const float* __restrict__ Wo,
    const float* __restrict__ W1, const float* __restrict__ W2, u16* __restrict__ Wt){
  __shared__ float sm[32][33];
  const int bid = blockIdx.x;
  const float* src; u16* dst; int R, C, tt;
  if(bid<2304){
    R=768; C=768; const int mi = bid/576; tt = bid - mi*576;
    src = (mi==0?Wq: mi==1?Wk: mi==2?Wv: Wo);
    dst = Wt + (size_t)mi*589824;
  } else if(bid<4608){ R=768; C=3072; tt=bid-2304; src=W1; dst=Wt+2359296; }
  else { R=3072; C=768; tt=bid-4608; src=W2; dst=Wt+4718592; }
  const int ntc=C>>5; const int tr=tt/ntc, tc=tt-tr*ntc;
  const int r0=tr<<5, c0=tc<<5, tx=threadIdx.x, ty2=threadIdx.y;
#pragma unroll
  for(int i=0;i<4;i++) sm[ty2+i*8][tx] = src[(size_t)(r0+ty2+i*8)*C + c0+tx];
  __syncthreads();
#pragma unroll
  for(int i=0;i<4;i++) dst[(size_t)(c0+ty2+i*8)*R + r0+tx] = f2bf(sm[tx][ty2+i*8]);
}

// ---------------------------------------------------------------- heads + CRF
__global__ void intent_kernel(const u16* __restrict__ x, const float* __restrict__ Wi,
    const float* __restrict__ bi, const int* __restrict__ lab, float* __restrict__ parts){
  const int b = blockIdx.x, t = threadIdx.x;
  __shared__ float xs[768];
  __shared__ float lg[10];
  const u16* rp = x + ((size_t)b*256)*768;
#pragma unroll
  for(int i=0;i<3;i++) xs[t+i*256] = bf2f(rp[t+i*256]);
  __syncthreads();
  if(t<10){
    float s = bi[t];
    for(int k=0;k<768;k++) s += xs[k]*Wi[(size_t)k*10 + t];
    lg[t] = s;
  }
  __syncthreads();
  if(t==0){
    float m = lg[0];
    for(int j=1;j<10;j++) m = fmaxf(m, lg[j]);
    float se = 0.f;
    for(int j=0;j<10;j++) se += expf(lg[j]-m);
    parts[b] = (logf(se) + m) - lg[lab[b]];
  }
}

__global__ __launch_bounds__(64)
void crf_kernel(const float* __restrict__ em, const int* __restrict__ tags,
    const int* __restrict__ amask, const float* __restrict__ cs, const float* __restrict__ ce,
    const float* __restrict__ tr, float* __restrict__ parts){
  const int b = blockIdx.x, j = threadIdx.x;
  const float* eb = em + (size_t)b*256*128;
  const int* tg = tags + b*256;
  const int* mk = amask + b*256;
  float Etr[64];
#pragma unroll
  for(int i=0;i<64;i++) Etr[i] = expf(tr[i*64 + j]);
  float sc = 0.f; int len = 0;
  for(int s=j+1; s<256; s+=64){
    const int pv = tg[s-1], cu = tg[s];
    sc += (tr[pv*64+cu] + eb[(size_t)s*128+cu]) * (float)mk[s];
  }
  for(int s=j; s<256; s+=64) len += mk[s];
#pragma unroll
  for(int dd=1; dd<64; dd<<=1){ sc += __shfl_xor(sc,dd); len += __shfl_xor(len,dd); }
  const int t0 = tg[0];
  float score = sc + cs[t0] + eb[t0] + ce[tg[len-1]];
  float alpha = cs[j] + eb[j];
  for(int s=1; s<256; s++){
    float am = alpha;
#pragma unroll
    for(int dd=1; dd<64; dd<<=1) am = fmaxf(am, __shfl_xor(am,dd));
    const float e = expf(alpha - am);
    float acc = 0.f;
#pragma unroll
    for(int i=0;i<64;i++) acc += __shfl(e, i) * Etr[i];
    const float nxt = logf(acc) + am + eb[(size_t)s*128 + j];
    alpha = (mk[s] > 0) ? nxt : alpha;
  }
  float v2 = alpha + ce[j];
  float am2 = v2;
#pragma unroll
  for(int dd=1; dd<64; dd<<=1) am2 = fmaxf(am2, __shfl_xor(am2,dd));
  float se = expf(v2 - am2);
#pragma unroll
  for(int dd=1; dd<64; dd<<=1) se += __shfl_xor(se,dd);
  if(j==0) parts[64+b] = (logf(se)+am2) - score;
}

__global__ void final_reduce(const float* __restrict__ parts, float* __restrict__ out){
  const int t = threadIdx.x;
  float a = parts[t], c = parts[64+t];
#pragma unroll
  for(int dd=1; dd<64; dd<<=1){ a += __shfl_xor(a,dd); c += __shfl_xor(c,dd); }
  if(t==0) out[0] = a*(1.f/64.f) + 2.f*c*(1.f/64.f);
}

// ---------------------------------------------------------------- host
extern "C" void kernel_launch(void* const* d_in, const int* in_sizes, int n_in,
                              void* d_out, int out_size, void* d_ws, size_t ws_size,
                              hipStream_t stream){
  (void)in_sizes; (void)n_in; (void)out_size;
  const int* ids   = (const int*)d_in[0];
  const int* amask = (const int*)d_in[1];
  const int* tti   = (const int*)d_in[2];
  const int* ilab  = (const int*)d_in[3];
  const int* slab  = (const int*)d_in[4];
  const float* we  = (const float*)d_in[5];
  const float* pe  = (const float*)d_in[6];
  const float* te  = (const float*)d_in[7];
  const float* eg  = (const float*)d_in[8];
  const float* ebt = (const float*)d_in[9];
  const float* Wq  = (const float*)d_in[10];
  const float* bq  = (const float*)d_in[11];
  const float* Wk  = (const float*)d_in[12];
  const float* bkk = (const float*)d_in[13];
  const float* Wv  = (const float*)d_in[14];
  const float* bvv = (const float*)d_in[15];
  const float* Wo  = (const float*)d_in[16];
  const float* bo  = (const float*)d_in[17];
  const float* l1g = (const float*)d_in[18];
  const float* l1b = (const float*)d_in[19];
  const float* W1  = (const float*)d_in[20];
  const float* b1  = (const float*)d_in[21];
  const float* W2  = (const float*)d_in[22];
  const float* b2  = (const float*)d_in[23];
  const float* l2g = (const float*)d_in[24];
  const float* l2b = (const float*)d_in[25];
  const float* Wi  = (const float*)d_in[26];
  const float* bi  = (const float*)d_in[27];
  const float* Wsp = (const float*)d_in[28];
  const float* bs  = (const float*)d_in[29];
  const float* cs  = (const float*)d_in[30];
  const float* ce  = (const float*)d_in[31];
  const float* ctr = (const float*)d_in[32];

  char* ws = (char*)d_ws;
  size_t off = 0;
  auto alloc = [&](size_t bytes)->void*{ void* p = ws + off; off += (bytes+255)&~(size_t)255; return p; };
  u16* x     = (u16*)alloc(16384ull*768*2);
  u16* h2    = (u16*)alloc(16384ull*768*2);
  u16* y     = (u16*)alloc(16384ull*768*2);
  u16* qkv   = (u16*)alloc(16384ull*2304*2);
  u16* cf    = (u16*)alloc(16384ull*3072*2);   // ctx (first 768 cols) / ff (3072 cols)
  u16* Wt    = (u16*)alloc(7077888ull*2);      // per-layer transposed bf16 weights
  u16* WsT   = (u16*)alloc(128ull*768*2);
  float* slots = (float*)alloc(16384ull*128*4);
  float* parts = (float*)alloc(512);
  if(off > ws_size) return; // insufficient workspace -> visible failure

  dim3 T256(256), T328(32,8);
  embed_ln<<<dim3(16384), T256, 0, stream>>>(ids, tti, we, pe, te, eg, ebt, x);
  transpose_cvt<<<dim3(48), T328, 0, stream>>>(Wsp, WsT, 768, 64);
  for(int L=0; L<12; L++){
    const size_t oH = (size_t)L*768*768, oF = (size_t)L*768*3072;
    conv_layer<<<dim3(6912), T328, 0, stream>>>(Wq+oH, Wk+oH, Wv+oH, Wo+oH, W1+oF, W2+oF, Wt);
    GemmP pq{ x, Wt, 768, qkv, 2304, bq+L*768, bkk+L*768, bvv+L*768, nullptr };
    gemm_bt<0><<<dim3(128,18), T256, 0, stream>>>(pq);
    attn_kernel<<<dim3(768), T256, 0, stream>>>(qkv, amask, cf);
    GemmP po{ cf, Wt+1769472, 768, y, 768, bo+L*768, nullptr, nullptr, x };
    gemm_bt<1><<<dim3(128,6), T256, 0, stream>>>(po);
    ln_kernel<<<dim3(16384), T256, 0, stream>>>(y, l1g+L*768, l1b+L*768, h2);
    GemmP p1{ h2, Wt+2359296, 768, cf, 3072, b1+L*3072, nullptr, nullptr, nullptr };
    gemm_bt<2><<<dim3(128,24), T256, 0, stream>>>(p1);
    GemmP p2{ cf, Wt+4718592, 3072, y, 768, b2+L*768, nullptr, nullptr, h2 };
    gemm_bt<1><<<dim3(128,6), T256, 0, stream>>>(p2);
    ln_kernel<<<dim3(16384), T256, 0, stream>>>(y, l2g+L*768, l2b+L*768, x);
  }
  GemmP psl{ x, WsT, 768, slots, 128, bs, nullptr, nullptr, nullptr };
  gemm_bt<3><<<dim3(128,1), T256, 0, stream>>>(psl);
  intent_kernel<<<dim3(64), T256, 0, stream>>>(x, Wi, bi, ilab, parts);
  crf_kernel<<<dim3(64), dim3(64), 0, stream>>>(slots, slab, amask, cs, ce, ctr, parts);
  final_reduce<<<dim3(1), dim3(64), 0, stream>>>(parts, (float*)d_out);
}

// Round 2
// 5480.648 us; speedup vs baseline: 1.1007x; 1.1007x over previous
//
#include <hip/hip_runtime.h>
#include <stdint.h>

typedef unsigned short u16;
typedef __attribute__((ext_vector_type(8))) short bh8;   // 8 x bf16 bits (4 VGPR)
typedef __attribute__((ext_vector_type(4))) float f4;    // 4 x f32 (4 VGPR)

#define DEV static __device__ __forceinline__

DEV u16 f2bf(float f){ union{float f; uint32_t u;} v; v.f=f; uint32_t r=v.u + 0x7FFFu + ((v.u>>16)&1u); return (u16)(r>>16); }
DEV float bf2f(u16 u){ union{uint32_t u; float f;} v; v.u=((uint32_t)u)<<16; return v.f; }

DEV void mfma16(f4& d, bh8 a, bh8 b){
  asm("v_mfma_f32_16x16x32_bf16 %0, %1, %2, %0" : "+v"(d) : "v"(a), "v"(b));
}

// MFMA->VALU hazard fence with data dependence on all 16 accumulators
#define FENCE16(A) asm volatile("s_nop 7\ns_nop 7" : \
 "+v"(A[0][0]),"+v"(A[0][1]),"+v"(A[0][2]),"+v"(A[0][3]),\
 "+v"(A[1][0]),"+v"(A[1][1]),"+v"(A[1][2]),"+v"(A[1][3]),\
 "+v"(A[2][0]),"+v"(A[2][1]),"+v"(A[2][2]),"+v"(A[2][3]),\
 "+v"(A[3][0]),"+v"(A[3][1]),"+v"(A[3][2]),"+v"(A[3][3]))

#define GLD16(g,l) __builtin_amdgcn_global_load_lds( \
    (__attribute__((address_space(1))) void*)(void*)(g), \
    (__attribute__((address_space(3))) void*)(void*)(l), 16, 0, 0)

// ---------------------------------------------------------------- GEMM
// C[M,N] = A[M,K](bf16,lda=K) * Bt[N,K](bf16,ldb=K)^T + epilogue
// 128x128 tile, BK=32, 4 waves each 64x64 (4x4 frags of 16x16x32)
struct GemmP { const u16* A; const u16* B; int K; void* C; int ldc;
               const float* b0; const float* b1; const float* b2; const u16* res; };

template<int EPI>
__global__ __launch_bounds__(256)
void gemm_bt(GemmP p){
  __shared__ __align__(16) u16 As[128*32];
  __shared__ __align__(16) u16 Bs[128*32];
  const int t=threadIdx.x, l=t&63, w=t>>6, wr=w>>1, wc=w&1;
  const int m0=blockIdx.x*128, n0=blockIdx.y*128;
  const u16* Ab = p.A + (size_t)m0*p.K;
  const u16* Bb = p.B + (size_t)n0*p.K;
  const int srow=l>>2, scol=(l&3)*8;
  f4 acc[4][4] = {};
  for(int k0=0;k0<p.K;k0+=32){
#pragma unroll
    for(int i=0;i<2;i++){
      const int c=w*2+i;
      GLD16(Ab + (size_t)(c*16+srow)*p.K + k0 + scol, &As[c*512]);
      GLD16(Bb + (size_t)(c*16+srow)*p.K + k0 + scol, &Bs[c*512]);
    }
    __syncthreads();
    bh8 af[4], bfr[4];
#pragma unroll
    for(int m=0;m<4;m++) af[m] = *(const bh8*)&As[(wr*64+m*16+(l&15))*32 + (l>>4)*8];
#pragma unroll
    for(int n=0;n<4;n++) bfr[n] = *(const bh8*)&Bs[(wc*64+n*16+(l&15))*32 + (l>>4)*8];
#pragma unroll
    for(int m=0;m<4;m++)
#pragma unroll
      for(int n=0;n<4;n++) mfma16(acc[m][n], af[m], bfr[n]);
    __syncthreads();
  }
  FENCE16(acc);
  const int lc=l&15, lr=(l>>4)*4;
#pragma unroll
  for(int m=0;m<4;m++)
#pragma unroll
  for(int n=0;n<4;n++)
#pragma unroll
  for(int r=0;r<4;r++){
    const int gr = m0 + wr*64 + m*16 + lr + r;
    const int gc = n0 + wc*64 + n*16 + lc;
    float v = acc[m][n][r];
    if(EPI==0){ // qkv: 3-way bias select, bf16 out
      const float* bp = (gc<768)? p.b0 : (gc<1536? p.b1 : p.b2);
      const int bc = (gc<768)? gc : (gc<1536? gc-768 : gc-1536);
      ((u16*)p.C)[(size_t)gr*p.ldc + gc] = f2bf(v + bp[bc]);
    } else if(EPI==1){ // bias + residual, bf16 out
      v += p.b0[gc] + bf2f(p.res[(size_t)gr*p.ldc + gc]);
      ((u16*)p.C)[(size_t)gr*p.ldc + gc] = f2bf(v);
    } else if(EPI==2){ // bias + exact GELU, bf16 out
      v += p.b0[gc];
      v = 0.5f*v*(1.f + erff(v*0.70710678118f));
      ((u16*)p.C)[(size_t)gr*p.ldc + gc] = f2bf(v);
    } else { // slots: bias (first 64 cols), f32 out
      v += (gc<64)? p.b0[gc] : 0.f;
      ((float*)p.C)[(size_t)gr*p.ldc + gc] = v;
    }
  }
}

// ---------------------------------------------------------------- attention
// one block per (b,head); flash-style over 4 key-tiles of 64
__global__ __launch_bounds__(256)
void attn_kernel(const u16* __restrict__ qkv, const int* __restrict__ amask, u16* __restrict__ ctx){
  __shared__ __align__(16) u16 Ks[256*64];   // [key][d], XOR-swizzled
  __shared__ __align__(16) u16 Vt[64*256];   // [d][key], XOR-swizzled
  __shared__ __align__(16) u16 Ps[4*64*64];  // per-wave P tile, swizzled
  __shared__ float biasS[256];
  const int t=threadIdx.x, l=t&63, w=t>>6;
  const int b=blockIdx.x/12, h=blockIdx.x%12;
  biasS[t] = (1.f - (float)amask[b*256+t]) * -1e9f;
  const u16* kb = qkv + ((size_t)b*256)*2304 + 768 + h*64;
  const u16* vb = kb + 768;
#pragma unroll
  for(int i=0;i<8;i++){
    const int c = t + i*256;
    const int row = c>>3, seg = c&7;
    uint4 kv = *(const uint4*)(kb + (size_t)row*2304 + seg*8);
    const int ba = row*128 + seg*16;
    *(uint4*)((char*)Ks + (ba ^ ((row&7)<<4))) = kv;
    uint4 vv = *(const uint4*)(vb + (size_t)row*2304 + seg*8);
    const u16* pv = (const u16*)&vv;
#pragma unroll
    for(int j=0;j<8;j++){
      const int d = seg*8+j;
      const int bb = d*512 + row*2;
      *(u16*)((char*)Vt + (bb ^ ((d&7)<<4))) = pv[j];
    }
  }
  bh8 aq[4][2];
  const u16* qb = qkv + ((size_t)b*256 + w*64)*2304 + h*64;
#pragma unroll
  for(int m=0;m<4;m++)
#pragma unroll
    for(int ks=0;ks<2;ks++)
      aq[m][ks] = *(const bh8*)(qb + (size_t)(m*16+(l&15))*2304 + ks*32 + (l>>4)*8);
  __syncthreads();
  float mrun[4][4], lrun[4][4];
  f4 o[4][4] = {};
#pragma unroll
  for(int m=0;m<4;m++)
#pragma unroll
    for(int r=0;r<4;r++){ mrun[m][r] = -3e38f; lrun[m][r]=0.f; }
  u16* Pw = Ps + w*4096;
  for(int kt=0;kt<4;kt++){
    f4 sacc[4][4] = {};
#pragma unroll
    for(int ks=0;ks<2;ks++)
#pragma unroll
      for(int n=0;n<4;n++){
        const int row = kt*64 + n*16 + (l&15);
        const int by = row*128 + ks*64 + (l>>4)*16;
        bh8 bk = *(const bh8*)((const char*)Ks + (by ^ ((row&7)<<4)));
#pragma unroll
        for(int m=0;m<4;m++) mfma16(sacc[m][n], aq[m][ks], bk);
      }
    FENCE16(sacc);
#pragma unroll
    for(int m=0;m<4;m++){
      float rmax[4] = {-3e38f,-3e38f,-3e38f,-3e38f};
#pragma unroll
      for(int n=0;n<4;n++){
        const float bi = biasS[kt*64 + n*16 + (l&15)];
#pragma unroll
        for(int r=0;r<4;r++){
          float sv = sacc[m][n][r]*0.125f + bi;   // 1/sqrt(64) + mask bias
          sacc[m][n][r] = sv;
          rmax[r] = fmaxf(rmax[r], sv);
        }
      }
#pragma unroll
      for(int dd=1; dd<16; dd<<=1)
#pragma unroll
        for(int r=0;r<4;r++) rmax[r] = fmaxf(rmax[r], __shfl_xor(rmax[r], dd));
      float psum[4];
#pragma unroll
      for(int r=0;r<4;r++){
        const float mn = fmaxf(mrun[m][r], rmax[r]);
        const float corr = __expf(mrun[m][r] - mn);
        mrun[m][r] = mn;
        lrun[m][r] *= corr;
#pragma unroll
        for(int nd=0; nd<4; nd++) o[m][nd][r] *= corr;
        psum[r] = 0.f;
      }
#pragma unroll
      for(int n=0;n<4;n++)
#pragma unroll
        for(int r=0;r<4;r++){
          const float pvv = __expf(sacc[m][n][r] - mrun[m][r]);
          sacc[m][n][r] = pvv;
          psum[r] += pvv;
        }
#pragma unroll
      for(int dd=1; dd<16; dd<<=1)
#pragma unroll
        for(int r=0;r<4;r++) psum[r] += __shfl_xor(psum[r], dd);
#pragma unroll
      for(int r=0;r<4;r++) lrun[m][r] += psum[r];
#pragma unroll
      for(int n=0;n<4;n++)
#pragma unroll
        for(int r=0;r<4;r++){
          const int prow = m*16 + (l>>4)*4 + r;
          const int pcol = n*16 + (l&15);
          const int by = prow*128 + pcol*2;
          *(u16*)((char*)Pw + (by ^ ((prow&7)<<4))) = f2bf(sacc[m][n][r]);
        }
    }
#pragma unroll
    for(int ks=0;ks<2;ks++){
      bh8 ap[4];
#pragma unroll
      for(int m=0;m<4;m++){
        const int prow = m*16 + (l&15);
        const int by = prow*128 + (ks*32 + (l>>4)*8)*2;
        ap[m] = *(const bh8*)((const char*)Pw + (by ^ ((prow&7)<<4)));
      }
#pragma unroll
      for(int nd=0; nd<4; nd++){
        const int dR = nd*16 + (l&15);
        const int by = dR*512 + (kt*64 + ks*32 + (l>>4)*8)*2;
        bh8 bv = *(const bh8*)((const char*)Vt + (by ^ ((dR&7)<<4)));
#pragma unroll
        for(int m=0;m<4;m++) mfma16(o[m][nd], ap[m], bv);
      }
    }
  }
  FENCE16(o);
#pragma unroll
  for(int m=0;m<4;m++)
#pragma unroll
  for(int nd=0; nd<4; nd++)
#pragma unroll
  for(int r=0;r<4;r++){
    const int row = w*64 + m*16 + (l>>4)*4 + r;
    const float vv = o[m][nd][r] / lrun[m][r];
    ctx[((size_t)b*256 + row)*768 + h*64 + nd*16 + (l&15)] = f2bf(vv);
  }
}

// ---------------------------------------------------------------- LN / embed
__global__ void ln_kernel(const u16* __restrict__ in, const float* __restrict__ g,
                          const float* __restrict__ b, u16* __restrict__ out){
  const int row = blockIdx.x, t = threadIdx.x;
  __shared__ float red[8];
  const u16* rp = in + (size_t)row*768;
  float v[3]; float s=0.f, q=0.f;
#pragma unroll
  for(int i=0;i<3;i++){ float x = bf2f(rp[t + i*256]); v[i]=x; s+=x; q+=x*x; }
#pragma unroll
  for(int dd=1; dd<64; dd<<=1){ s += __shfl_xor(s,dd); q += __shfl_xor(q,dd); }
  if((t&63)==0){ red[t>>6]=s; red[4+(t>>6)]=q; }
  __syncthreads();
  s = red[0]+red[1]+red[2]+red[3];
  q = red[4]+red[5]+red[6]+red[7];
  const float mean = s*(1.f/768.f);
  float var = q*(1.f/768.f) - mean*mean; var = fmaxf(var, 0.f);
  const float rs = rsqrtf(var + 1e-12f);
  u16* op = out + (size_t)row*768;
#pragma unroll
  for(int i=0;i<3;i++){ const int hh=t+i*256; op[hh] = f2bf((v[i]-mean)*rs*g[hh] + b[hh]); }
}

__global__ void embed_ln(const int* __restrict__ ids, const int* __restrict__ tti,
    const float* __restrict__ we, const float* __restrict__ pe, const float* __restrict__ te,
    const float* __restrict__ g, const float* __restrict__ bb, u16* __restrict__ x){
  const int tok = blockIdx.x, t = threadIdx.x;
  __shared__ float red[8];
  const int id = ids[tok], tyid = tti[tok], s0 = tok & 255;
  float v[3]; float s=0.f,q=0.f;
#pragma unroll
  for(int i=0;i<3;i++){
    const int hh = t+i*256;
    float x0 = we[(size_t)id*768+hh] + pe[(size_t)s0*768+hh] + te[(size_t)tyid*768+hh];
    v[i]=x0; s+=x0; q+=x0*x0;
  }
#pragma unroll
  for(int dd=1; dd<64; dd<<=1){ s += __shfl_xor(s,dd); q += __shfl_xor(q,dd); }
  if((t&63)==0){ red[t>>6]=s; red[4+(t>>6)]=q; }
  __syncthreads();
  s = red[0]+red[1]+red[2]+red[3];
  q = red[4]+red[5]+red[6]+red[7];
  const float mean = s*(1.f/768.f);
  float var = q*(1.f/768.f) - mean*mean; var = fmaxf(var, 0.f);
  const float rs = rsqrtf(var + 1e-12f);
#pragma unroll
  for(int i=0;i<3;i++){ const int hh=t+i*256; x[(size_t)tok*768+hh] = f2bf((v[i]-mean)*rs*g[hh] + bb[hh]); }
}

// ---------------------------------------------------------------- weight transpose+cvt
__global__ void transpose_cvt(const float* __restrict__ src, u16* __restrict__ dst, int R, int C){
  __shared__ float sm[32][33];
  const int ntc = C>>5;
  const int tr = blockIdx.x/ntc, tc = blockIdx.x - tr*ntc;
  const int r0 = tr<<5, c0 = tc<<5;
  const int tx = threadIdx.x, ty2 = threadIdx.y;
#pragma unroll
  for(int i=0;i<4;i++) sm[ty2+i*8][tx] = src[(size_t)(r0+ty2+i*8)*C + c0+tx];
  __syncthreads();
#pragma unroll
  for(int i=0;i<4;i++) dst[(size_t)(c0+ty2+i*8)*R + r0+tx] = f2bf(sm[tx][ty2+i*8]);
}

__global__ void conv_layer(const float* __restrict__ Wq, const float* __restrict__ Wk,
    const float* __restrict__ Wv, const float* __restrict__ Wo,
    const float* __restrict__ W1, const float* __restrict__ W2, u16* __restrict__ Wt){
  __shared__ float sm[32][33];
  const int bid = blockIdx.x;
  const float* src; u16* dst; int R, C, tt;
  if(bid<2304){
    R=768; C=768; const int mi = bid/576; tt = bid - mi*576;
    src = (mi==0?Wq: mi==1?Wk: mi==2?Wv: Wo);
    dst = Wt + (size_t)mi*589824;
  } else if(bid<4608){ R=768; C=3072; tt=bid-2304; src=W1; dst=Wt+2359296; }
  else { R=3072; C=768; tt=bid-4608; src=W2; dst=Wt+4718592; }
  const int ntc=C>>5; const int tr=tt/ntc, tc=tt-tr*ntc;
  const int r0=tr<<5, c0=tc<<5, tx=threadIdx.x, ty2=threadIdx.y;
#pragma unroll
  for(int i=0;i<4;i++) sm[ty2+i*8][tx] = src[(size_t)(r0+ty2+i*8)*C + c0+tx];
  __syncthreads();
#pragma unroll
  for(int i=0;i<4;i++) dst[(size_t)(c0+ty2+i*8)*R + r0+tx] = f2bf(sm[tx][ty2+i*8]);
}

// ---------------------------------------------------------------- heads + CRF
__global__ void intent_kernel(const u16* __restrict__ x, const float* __restrict__ Wi,
    const float* __restrict__ bi, const int* __restrict__ lab, float* __restrict__ parts){
  const int b = blockIdx.x, t = threadIdx.x;
  __shared__ float xs[768];
  __shared__ float lg[10];
  const u16* rp = x + ((size_t)b*256)*768;
#pragma unroll
  for(int i=0;i<3;i++) xs[t+i*256] = bf2f(rp[t+i*256]);
  __syncthreads();
  if(t<10){
    float s = bi[t];
    for(int k=0;k<768;k++) s += xs[k]*Wi[(size_t)k*10 + t];
    lg[t] = s;
  }
  __syncthreads();
  if(t==0){
    float m = lg[0];
    for(int j=1;j<10;j++) m = fmaxf(m, lg[j]);
    float se = 0.f;
    for(int j=0;j<10;j++) se += expf(lg[j]-m);
    parts[b] = (logf(se) + m) - lg[lab[b]];
  }
}

// CRF forward scan in the LINEAR domain: a' = (E^T a) * exp(em_s),
// E = exp(trans) held per-lane (column j), a broadcast via LDS float4 reads.
// Scalar renorm (lane0) every 8 steps keeps fp32 in range; logc accumulates.
__global__ __launch_bounds__(64)
void crf_kernel(const float* __restrict__ em, const int* __restrict__ tags,
    const int* __restrict__ amask, const float* __restrict__ cs, const float* __restrict__ ce,
    const float* __restrict__ tr, float* __restrict__ parts){
  const int b = blockIdx.x, j = threadIdx.x;
  const float* eb = em + (size_t)b*256*128;
  const int* tg = tags + b*256;
  const int* mk = amask + b*256;
  __shared__ __align__(16) float aS[64];
  float Etr[64];
#pragma unroll
  for(int i=0;i<64;i++) Etr[i] = __expf(tr[i*64 + j]);
  // gold-path score
  float sc = 0.f; int len = 0;
  for(int s=j+1; s<256; s+=64){
    const int pv = tg[s-1], cu = tg[s];
    sc += (tr[pv*64+cu] + eb[(size_t)s*128+cu]) * (float)mk[s];
  }
  for(int s=j; s<256; s+=64) len += mk[s];
#pragma unroll
  for(int dd=1; dd<64; dd<<=1){ sc += __shfl_xor(sc,dd); len += __shfl_xor(len,dd); }
  const int t0 = tg[0];
  float score = sc + cs[t0] + eb[t0] + ce[tg[len-1]];
  // forward scan
  float a = __expf(cs[j] + eb[j]);
  float logc = 0.f;
  float em_s = eb[128 + j];
  int   mk_s = mk[1];
  for(int s=1; s<256; s++){
    const int sn = (s<255)? s+1 : s;
    const float em_n = eb[(size_t)sn*128 + j];   // prefetch next step
    const int   mk_n = mk[sn];
    aS[j] = a;
    __syncthreads();
    float acc0=0.f, acc1=0.f, acc2=0.f, acc3=0.f;
    const float4* ap = (const float4*)aS;
#pragma unroll
    for(int q2=0;q2<16;q2++){
      const float4 av = ap[q2];   // broadcast read, conflict-free
      acc0 += av.x*Etr[4*q2+0];
      acc1 += av.y*Etr[4*q2+1];
      acc2 += av.z*Etr[4*q2+2];
      acc3 += av.w*Etr[4*q2+3];
    }
    __syncthreads();
    const float nxt = ((acc0+acc1)+(acc2+acc3)) * __expf(em_s);
    a = (mk_s > 0) ? nxt : a;
    if((s&7)==7){
      const float c = __shfl(a, 0);
      logc += __logf(c);
      a *= (1.f/c);
    }
    em_s = em_n; mk_s = mk_n;
  }
  float v2 = logf(a) + logc + ce[j];
  float am2 = v2;
#pragma unroll
  for(int dd=1; dd<64; dd<<=1) am2 = fmaxf(am2, __shfl_xor(am2,dd));
  float se = __expf(v2 - am2);
#pragma unroll
  for(int dd=1; dd<64; dd<<=1) se += __shfl_xor(se,dd);
  if(j==0) parts[64+b] = (logf(se)+am2) - score;
}

__global__ void final_reduce(const float* __restrict__ parts, float* __restrict__ out){
  const int t = threadIdx.x;
  float a = parts[t], c = parts[64+t];
#pragma unroll
  for(int dd=1; dd<64; dd<<=1){ a += __shfl_xor(a,dd); c += __shfl_xor(c,dd); }
  if(t==0) out[0] = a*(1.f/64.f) + 2.f*c*(1.f/64.f);
}

// ---------------------------------------------------------------- host
extern "C" void kernel_launch(void* const* d_in, const int* in_sizes, int n_in,
                              void* d_out, int out_size, void* d_ws, size_t ws_size,
                              hipStream_t stream){
  (void)in_sizes; (void)n_in; (void)out_size;
  const int* ids   = (const int*)d_in[0];
  const int* amask = (const int*)d_in[1];
  const int* tti   = (const int*)d_in[2];
  const int* ilab  = (const int*)d_in[3];
  const int* slab  = (const int*)d_in[4];
  const float* we  = (const float*)d_in[5];
  const float* pe  = (const float*)d_in[6];
  const float* te  = (const float*)d_in[7];
  const float* eg  = (const float*)d_in[8];
  const float* ebt = (const float*)d_in[9];
  const float* Wq  = (const float*)d_in[10];
  const float* bq  = (const float*)d_in[11];
  const float* Wk  = (const float*)d_in[12];
  const float* bkk = (const float*)d_in[13];
  const float* Wv  = (const float*)d_in[14];
  const float* bvv = (const float*)d_in[15];
  const float* Wo  = (const float*)d_in[16];
  const float* bo  = (const float*)d_in[17];
  const float* l1g = (const float*)d_in[18];
  const float* l1b = (const float*)d_in[19];
  const float* W1  = (const float*)d_in[20];
  const float* b1  = (const float*)d_in[21];
  const float* W2  = (const float*)d_in[22];
  const float* b2  = (const float*)d_in[23];
  const float* l2g = (const float*)d_in[24];
  const float* l2b = (const float*)d_in[25];
  const float* Wi  = (const float*)d_in[26];
  const float* bi  = (const float*)d_in[27];
  const float* Wsp = (const float*)d_in[28];
  const float* bs  = (const float*)d_in[29];
  const float* cs  = (const float*)d_in[30];
  const float* ce  = (const float*)d_in[31];
  const float* ctr = (const float*)d_in[32];

  char* ws = (char*)d_ws;
  size_t off = 0;
  auto alloc = [&](size_t bytes)->void*{ void* p = ws + off; off += (bytes+255)&~(size_t)255; return p; };
  u16* x     = (u16*)alloc(16384ull*768*2);
  u16* h2    = (u16*)alloc(16384ull*768*2);
  u16* y     = (u16*)alloc(16384ull*768*2);
  u16* qkv   = (u16*)alloc(16384ull*2304*2);
  u16* cf    = (u16*)alloc(16384ull*3072*2);   // ctx (first 768 cols) / ff (3072 cols)
  u16* Wt    = (u16*)alloc(7077888ull*2);      // per-layer transposed bf16 weights
  u16* WsT   = (u16*)alloc(128ull*768*2);
  float* slots = (float*)alloc(16384ull*128*4);
  float* parts = (float*)alloc(512);
  if(off > ws_size) return; // insufficient workspace -> visible failure

  dim3 T256(256), T328(32,8);
  embed_ln<<<dim3(16384), T256, 0, stream>>>(ids, tti, we, pe, te, eg, ebt, x);
  transpose_cvt<<<dim3(48), T328, 0, stream>>>(Wsp, WsT, 768, 64);
  for(int L=0; L<12; L++){
    const size_t oH = (size_t)L*768*768, oF = (size_t)L*768*3072;
    conv_layer<<<dim3(6912), T328, 0, stream>>>(Wq+oH, Wk+oH, Wv+oH, Wo+oH, W1+oF, W2+oF, Wt);
    GemmP pq{ x, Wt, 768, qkv, 2304, bq+L*768, bkk+L*768, bvv+L*768, nullptr };
    gemm_bt<0><<<dim3(128,18), T256, 0, stream>>>(pq);
    attn_kernel<<<dim3(768), T256, 0, stream>>>(qkv, amask, cf);
    GemmP po{ cf, Wt+1769472, 768, y, 768, bo+L*768, nullptr, nullptr, x };
    gemm_bt<1><<<dim3(128,6), T256, 0, stream>>>(po);
    ln_kernel<<<dim3(16384), T256, 0, stream>>>(y, l1g+L*768, l1b+L*768, h2);
    GemmP p1{ h2, Wt+2359296, 768, cf, 3072, b1+L*3072, nullptr, nullptr, nullptr };
    gemm_bt<2><<<dim3(128,24), T256, 0, stream>>>(p1);
    GemmP p2{ cf, Wt+4718592, 3072, y, 768, b2+L*768, nullptr, nullptr, h2 };
    gemm_bt<1><<<dim3(128,6), T256, 0, stream>>>(p2);
    ln_kernel<<<dim3(16384), T256, 0, stream>>>(y, l2g+L*768, l2b+L*768, x);
  }
  GemmP psl{ x, WsT, 768, slots, 128, bs, nullptr, nullptr, nullptr };
  gemm_bt<3><<<dim3(128,1), T256, 0, stream>>>(psl);
  intent_kernel<<<dim3(64), T256, 0, stream>>>(x, Wi, bi, ilab, parts);
  crf_kernel<<<dim3(64), dim3(64), 0, stream>>>(slots, slab, amask, cs, ce, ctr, parts);
  final_reduce<<<dim3(1), dim3(64), 0, stream>>>(parts, (float*)d_out);
}